// Round 11
// baseline (403.851 us; speedup 1.0000x reference)
//
#include <hip/hip_runtime.h>

// AffinityPropagate (CSPN): B=8, C=32, H=W=256, K=3, prop_time=16.
// R10: R9 (planar coalesced weights + shfl halos, CPB=2) with STRIP 16->8:
// mid 36 KB -> 20.5 KB => 7 blocks/CU (28 waves) instead of 4 (16 waves).
// Single-variable occupancy test now that the weight-load pathology is gone.

#define B_ 8
#define C_ 32
#define H_ 256
#define W_ 256
#define STRIP 8
#define CPB 2
#define MIDR (STRIP + 2)

// Planar weights: wts[((b*9)+j)*H*W + h*W + w]
__global__ __launch_bounds__(256)
void prep_weights_kernel(const float* __restrict__ guided,
                         const float* __restrict__ depth,
                         float* __restrict__ wts,
                         int total /* B*H*W */) {
    int idx = blockIdx.x * 256 + threadIdx.x;
    if (idx >= total) return;
    int b  = idx >> 16;        // H*W = 65536
    int hw = idx & 0xFFFF;
    const float* gp = guided + (((size_t)b * 8) << 16) + hw;
    float g[8];
    float m = -3.4e38f;
#pragma unroll
    for (int j = 0; j < 8; j++) { g[j] = gp[(size_t)j << 16]; m = fmaxf(m, g[j]); }
    float s = 0.f;
#pragma unroll
    for (int j = 0; j < 8; j++) { g[j] = expf(g[j] - m); s += g[j]; }
    float inv = 1.0f / s;
    float d = depth[(((size_t)b) << 16) + hw];
    bool fixed = d > 0.f;   // sign(depth) is 0/1 (depth >= 0)
    float* wp = wts + (((size_t)b * 9) << 16) + hw;
#pragma unroll
    for (int j = 0; j < 9; j++) {
        float v;
        if (j == 4) v = fixed ? 1.f : 0.f;            // center
        else        v = fixed ? 0.f : g[j - (j > 4 ? 1 : 0)] * inv;
        wp[(size_t)j << 16] = v;
    }
}

// acc[k] += wgt[3i+j][k] * rb[i][k+j]  — same fmaf order as R3/R4/R9 (passed).
__device__ __forceinline__ void stencil4(const float wgt[9][4],
                                         const float rb[3][6],
                                         float acc[4]) {
#pragma unroll
    for (int i = 0; i < 3; ++i)
#pragma unroll
        for (int j = 0; j < 3; ++j)
#pragma unroll
            for (int k = 0; k < 4; ++k)
                acc[k] = fmaf(wgt[i * 3 + j][k], rb[i][k + j], acc[k]);
}

// Two fused propagation steps. Block (64,4): one wave == one full 256-wide
// row (64 lanes x 4 px). Halos via wave shfl (no scalar loads, 0 conflicts).
__global__ __launch_bounds__(256)
void prop2_kernel(const float* __restrict__ xin,
                  const float* __restrict__ wts,
                  float* __restrict__ xout) {
    __shared__ float mid[CPB][MIDR][W_];   // 20.5 KB
    const int tx = threadIdx.x;            // 0..63
    const int ty = threadIdx.y;            // 0..3
    const int h0 = blockIdx.x * STRIP;
    const int c0 = blockIdx.y * CPB;
    const int b  = blockIdx.z;
    const int w0 = tx * 4;
    const size_t plane = (size_t)H_ * W_;
    const bool hasL = (tx > 0), hasR = (tx < 63);

    // ---- Phase 1: step-1 on rows h0-1 .. h0+STRIP, into LDS ----
    for (int rr = ty; rr < MIDR; rr += 4) {
        const int r = h0 - 1 + rr;
        if (r < 0 || r >= H_) {
            float4 z = {0.f, 0.f, 0.f, 0.f};
#pragma unroll
            for (int c = 0; c < CPB; ++c)
                *reinterpret_cast<float4*>(&mid[c][rr][w0]) = z;
            continue;
        }
        // planar weights: 9 fully-coalesced float4 loads (1KB/wave each)
        const float* wp = wts + (size_t)b * 9 * plane + (size_t)r * W_ + w0;
        float wgt[9][4];
#pragma unroll
        for (int j = 0; j < 9; ++j) {
            float4 v = *reinterpret_cast<const float4*>(wp + j * plane);
            wgt[j][0] = v.x; wgt[j][1] = v.y; wgt[j][2] = v.z; wgt[j][3] = v.w;
        }
#pragma unroll
        for (int c = 0; c < CPB; ++c) {
            const float* xc = xin + ((size_t)b * C_ + (c0 + c)) * plane;
            float rb[3][6];
#pragma unroll
            for (int i = 0; i < 3; ++i) {
                int row = r - 1 + i;
                if (row >= 0 && row < H_) {
                    float4 v = *reinterpret_cast<const float4*>(
                        xc + (size_t)row * W_ + w0);
                    float lh = __shfl_up(v.w, 1);
                    float rhv = __shfl_down(v.x, 1);
                    rb[i][0] = hasL ? lh : 0.f;
                    rb[i][1] = v.x; rb[i][2] = v.y; rb[i][3] = v.z; rb[i][4] = v.w;
                    rb[i][5] = hasR ? rhv : 0.f;
                } else {
#pragma unroll
                    for (int t = 0; t < 6; ++t) rb[i][t] = 0.f;
                }
            }
            float acc[4] = {0.f, 0.f, 0.f, 0.f};
            stencil4(wgt, rb, acc);
            float4 o = {acc[0], acc[1], acc[2], acc[3]};
            *reinterpret_cast<float4*>(&mid[c][rr][w0]) = o;
        }
    }
    __syncthreads();

    // ---- Phase 2: step-2 on rows h0 .. h0+STRIP-1, LDS -> global ----
    for (int rr = ty; rr < STRIP; rr += 4) {
        const int r = h0 + rr;
        const float* wp = wts + (size_t)b * 9 * plane + (size_t)r * W_ + w0;
        float wgt[9][4];
#pragma unroll
        for (int j = 0; j < 9; ++j) {
            float4 v = *reinterpret_cast<const float4*>(wp + j * plane);
            wgt[j][0] = v.x; wgt[j][1] = v.y; wgt[j][2] = v.z; wgt[j][3] = v.w;
        }
#pragma unroll
        for (int c = 0; c < CPB; ++c) {
            float rb[3][6];
#pragma unroll
            for (int i = 0; i < 3; ++i) {
                // mid index rr+i corresponds to global row r-1+i
                float4 v = *reinterpret_cast<const float4*>(&mid[c][rr + i][w0]);
                float lh = __shfl_up(v.w, 1);
                float rhv = __shfl_down(v.x, 1);
                rb[i][0] = hasL ? lh : 0.f;
                rb[i][1] = v.x; rb[i][2] = v.y; rb[i][3] = v.z; rb[i][4] = v.w;
                rb[i][5] = hasR ? rhv : 0.f;
            }
            float acc[4] = {0.f, 0.f, 0.f, 0.f};
            stencil4(wgt, rb, acc);
            float4 o = {acc[0], acc[1], acc[2], acc[3]};
            *reinterpret_cast<float4*>(xout + ((size_t)b * C_ + (c0 + c)) * plane +
                                       (size_t)r * W_ + w0) = o;
        }
    }
}

extern "C" void kernel_launch(void* const* d_in, const int* in_sizes, int n_in,
                              void* d_out, int out_size, void* d_ws, size_t ws_size,
                              hipStream_t stream) {
    const float* x      = (const float*)d_in[0];
    const float* guided = (const float*)d_in[1];
    const float* depth  = (const float*)d_in[2];
    // d_in[3] = prop_time; fixed to 16 by setup_inputs.
    const int FUSED_STEPS = 8;   // 16 propagation steps, 2 per kernel

    float* xbuf = (float*)d_ws;                                   // 64 MB
    float* wts  = (float*)((char*)d_ws +
                           (size_t)B_ * C_ * H_ * W_ * sizeof(float)); // 18.9 MB
    float* out  = (float*)d_out;

    int total = B_ * H_ * W_;
    hipLaunchKernelGGL(prep_weights_kernel, dim3((total + 255) / 256), dim3(256),
                       0, stream, guided, depth, wts, total);

    dim3 grid(H_ / STRIP, C_ / CPB, B_), block(64, 4, 1);
    const float* src = x;
    for (int t = 0; t < FUSED_STEPS; ++t) {
        float* dst = (t == FUSED_STEPS - 1) ? out : ((t % 2 == 0) ? xbuf : out);
        hipLaunchKernelGGL(prop2_kernel, grid, block, 0, stream,
                           src, wts, dst);
        src = dst;
    }
}

// Round 12
// 349.178 us; speedup vs baseline: 1.1566x; 1.1566x over previous
//
#include <hip/hip_runtime.h>

// AffinityPropagate (CSPN): B=8, C=32, H=W=256, K=3, prop_time=16.
// R11: R9 config (planar weights, shfl halos, CPB=2, STRIP=16) + XCD-aware
// block remap: grid 2048 = 8 XCDs x 256; logical order (b, h, c-fastest)
// chunked so XCD k owns batch k -> its 2.36 MB weight set stays L2-resident
// (was re-read ~34x/step from LLC = the steady-state limiter).

#define B_ 8
#define C_ 32
#define H_ 256
#define W_ 256
#define STRIP 16
#define CPB 2
#define MIDR (STRIP + 2)

// Planar weights: wts[((b*9)+j)*H*W + h*W + w]
__global__ __launch_bounds__(256)
void prep_weights_kernel(const float* __restrict__ guided,
                         const float* __restrict__ depth,
                         float* __restrict__ wts,
                         int total /* B*H*W */) {
    int idx = blockIdx.x * 256 + threadIdx.x;
    if (idx >= total) return;
    int b  = idx >> 16;        // H*W = 65536
    int hw = idx & 0xFFFF;
    const float* gp = guided + (((size_t)b * 8) << 16) + hw;
    float g[8];
    float m = -3.4e38f;
#pragma unroll
    for (int j = 0; j < 8; j++) { g[j] = gp[(size_t)j << 16]; m = fmaxf(m, g[j]); }
    float s = 0.f;
#pragma unroll
    for (int j = 0; j < 8; j++) { g[j] = expf(g[j] - m); s += g[j]; }
    float inv = 1.0f / s;
    float d = depth[(((size_t)b) << 16) + hw];
    bool fixed = d > 0.f;   // sign(depth) is 0/1 (depth >= 0)
    float* wp = wts + (((size_t)b * 9) << 16) + hw;
#pragma unroll
    for (int j = 0; j < 9; j++) {
        float v;
        if (j == 4) v = fixed ? 1.f : 0.f;            // center
        else        v = fixed ? 0.f : g[j - (j > 4 ? 1 : 0)] * inv;
        wp[(size_t)j << 16] = v;
    }
}

// acc[k] += wgt[3i+j][k] * rb[i][k+j]  — same fmaf order as R3/R4/R9 (passed).
__device__ __forceinline__ void stencil4(const float wgt[9][4],
                                         const float rb[3][6],
                                         float acc[4]) {
#pragma unroll
    for (int i = 0; i < 3; ++i)
#pragma unroll
        for (int j = 0; j < 3; ++j)
#pragma unroll
            for (int k = 0; k < 4; ++k)
                acc[k] = fmaf(wgt[i * 3 + j][k], rb[i][k + j], acc[k]);
}

// Two fused propagation steps. Block (64,4): one wave == one full 256-wide
// row. Halos via wave shfl. 1D grid of 2048 with XCD-aware decode.
__global__ __launch_bounds__(256)
void prop2_kernel(const float* __restrict__ xin,
                  const float* __restrict__ wts,
                  float* __restrict__ xout) {
    __shared__ float mid[CPB][MIDR][W_];   // 36 KB
    // XCD-aware remap: physical p -> xcd = p%8 owns contiguous logical chunk.
    // logical = (b*16 + hblk)*16 + cblk  (c fastest). XCD k => batch k.
    const int p    = blockIdx.x;           // 0..2047
    const int xcd  = p & 7;
    const int slot = p >> 3;               // 0..255
    const int logical = (xcd << 8) + slot;
    const int cblk = logical & 15;
    const int tt   = logical >> 4;
    const int hblk = tt & 15;
    const int b    = tt >> 4;

    const int tx = threadIdx.x;            // 0..63
    const int ty = threadIdx.y;            // 0..3
    const int h0 = hblk * STRIP;
    const int c0 = cblk * CPB;
    const int w0 = tx * 4;
    const size_t plane = (size_t)H_ * W_;
    const bool hasL = (tx > 0), hasR = (tx < 63);

    // ---- Phase 1: step-1 on rows h0-1 .. h0+STRIP, into LDS ----
    for (int rr = ty; rr < MIDR; rr += 4) {
        const int r = h0 - 1 + rr;
        if (r < 0 || r >= H_) {
            float4 z = {0.f, 0.f, 0.f, 0.f};
#pragma unroll
            for (int c = 0; c < CPB; ++c)
                *reinterpret_cast<float4*>(&mid[c][rr][w0]) = z;
            continue;
        }
        // planar weights: 9 fully-coalesced float4 loads (1KB/wave each)
        const float* wp = wts + (size_t)b * 9 * plane + (size_t)r * W_ + w0;
        float wgt[9][4];
#pragma unroll
        for (int j = 0; j < 9; ++j) {
            float4 v = *reinterpret_cast<const float4*>(wp + j * plane);
            wgt[j][0] = v.x; wgt[j][1] = v.y; wgt[j][2] = v.z; wgt[j][3] = v.w;
        }
#pragma unroll
        for (int c = 0; c < CPB; ++c) {
            const float* xc = xin + ((size_t)b * C_ + (c0 + c)) * plane;
            float rb[3][6];
#pragma unroll
            for (int i = 0; i < 3; ++i) {
                int row = r - 1 + i;
                if (row >= 0 && row < H_) {
                    float4 v = *reinterpret_cast<const float4*>(
                        xc + (size_t)row * W_ + w0);
                    float lh = __shfl_up(v.w, 1);
                    float rhv = __shfl_down(v.x, 1);
                    rb[i][0] = hasL ? lh : 0.f;
                    rb[i][1] = v.x; rb[i][2] = v.y; rb[i][3] = v.z; rb[i][4] = v.w;
                    rb[i][5] = hasR ? rhv : 0.f;
                } else {
#pragma unroll
                    for (int t = 0; t < 6; ++t) rb[i][t] = 0.f;
                }
            }
            float acc[4] = {0.f, 0.f, 0.f, 0.f};
            stencil4(wgt, rb, acc);
            float4 o = {acc[0], acc[1], acc[2], acc[3]};
            *reinterpret_cast<float4*>(&mid[c][rr][w0]) = o;
        }
    }
    __syncthreads();

    // ---- Phase 2: step-2 on rows h0 .. h0+STRIP-1, LDS -> global ----
    for (int rr = ty; rr < STRIP; rr += 4) {
        const int r = h0 + rr;
        const float* wp = wts + (size_t)b * 9 * plane + (size_t)r * W_ + w0;
        float wgt[9][4];
#pragma unroll
        for (int j = 0; j < 9; ++j) {
            float4 v = *reinterpret_cast<const float4*>(wp + j * plane);
            wgt[j][0] = v.x; wgt[j][1] = v.y; wgt[j][2] = v.z; wgt[j][3] = v.w;
        }
#pragma unroll
        for (int c = 0; c < CPB; ++c) {
            float rb[3][6];
#pragma unroll
            for (int i = 0; i < 3; ++i) {
                // mid index rr+i corresponds to global row r-1+i
                float4 v = *reinterpret_cast<const float4*>(&mid[c][rr + i][w0]);
                float lh = __shfl_up(v.w, 1);
                float rhv = __shfl_down(v.x, 1);
                rb[i][0] = hasL ? lh : 0.f;
                rb[i][1] = v.x; rb[i][2] = v.y; rb[i][3] = v.z; rb[i][4] = v.w;
                rb[i][5] = hasR ? rhv : 0.f;
            }
            float acc[4] = {0.f, 0.f, 0.f, 0.f};
            stencil4(wgt, rb, acc);
            float4 o = {acc[0], acc[1], acc[2], acc[3]};
            *reinterpret_cast<float4*>(xout + ((size_t)b * C_ + (c0 + c)) * plane +
                                       (size_t)r * W_ + w0) = o;
        }
    }
}

extern "C" void kernel_launch(void* const* d_in, const int* in_sizes, int n_in,
                              void* d_out, int out_size, void* d_ws, size_t ws_size,
                              hipStream_t stream) {
    const float* x      = (const float*)d_in[0];
    const float* guided = (const float*)d_in[1];
    const float* depth  = (const float*)d_in[2];
    // d_in[3] = prop_time; fixed to 16 by setup_inputs.
    const int FUSED_STEPS = 8;   // 16 propagation steps, 2 per kernel

    float* xbuf = (float*)d_ws;                                   // 64 MB
    float* wts  = (float*)((char*)d_ws +
                           (size_t)B_ * C_ * H_ * W_ * sizeof(float)); // 18.9 MB
    float* out  = (float*)d_out;

    int total = B_ * H_ * W_;
    hipLaunchKernelGGL(prep_weights_kernel, dim3((total + 255) / 256), dim3(256),
                       0, stream, guided, depth, wts, total);

    // 1D grid: 16 hstrips * 16 cblocks * 8 batches = 2048 = 8 XCDs * 256
    dim3 grid(2048, 1, 1), block(64, 4, 1);
    const float* src = x;
    for (int t = 0; t < FUSED_STEPS; ++t) {
        float* dst = (t == FUSED_STEPS - 1) ? out : ((t % 2 == 0) ? xbuf : out);
        hipLaunchKernelGGL(prop2_kernel, grid, block, 0, stream,
                           src, wts, dst);
        src = dst;
    }
}